// Round 7
// baseline (176.650 us; speedup 1.0000x reference)
//
#include <hip/hip_runtime.h>
#include <math.h>

typedef __bf16 bf16;
typedef __bf16 bf16x8 __attribute__((ext_vector_type(8)));
typedef float  f32x4  __attribute__((ext_vector_type(4)));

#define DEV __device__ __forceinline__
#define VMCNT(n) asm volatile("s_waitcnt vmcnt(" #n ")" ::: "memory")
#define CFENCE  asm volatile("" ::: "memory")
#define BAR()   { CFENCE; __builtin_amdgcn_s_barrier(); CFENCE; }

DEV void gload_lds16(const bf16* g, bf16* l) {
  __builtin_amdgcn_global_load_lds(
      (const __attribute__((address_space(1))) void*)g,
      (__attribute__((address_space(3))) void*)l, 16, 0, 0);
}

// ---------------- workspace layout (bytes) ----------------
// persistent through out-proj: stats, wot. Everything else phase-scoped.
#define OFF_STATS 0UL
#define OFF_WOT   1024UL        // 512*512*2 = 524288            -> 525312
#define OFF_BIASQ 525312UL      // 1536*4    = 6144              -> 531456
#define OFF_WTQKV 531456UL      // 1536*512*2 = 1572864          -> 2104320
#define OFF_XN    2104320UL     // 8192*512*2 = 8388608          -> 10492928
#define OFF_QKV   10492928UL    // 8192*1536*2 = 25165824        -> 35658752
#define OFF_VT    35658752UL    // 2*512*4096*2 = 8388608        -> 44047360
#define OFF_S     44047360UL    // 2*4096*4096*2 = 67108864      -> 111156224
// overlays (stream-ordered lifetimes):
#define OFF_P0    2104320UL     // f32 2*4096*512*4 = 16777216 (xn/qkv dead at PV)
#define OFF_P1    18881536UL    // ends 35658752 == OFF_VT exactly
#define OFF_ATTN  44047360UL    // overlays S (dead after PV; reduce runs after)
#define OFF_GNP   44047360UL    // gn partials, prep-time only

// ---------------- GroupNorm partial stats: 1024 blocks ----------------
__global__ __launch_bounds__(256) void gn_part_k(const float* __restrict__ x,
                                                 float2* __restrict__ part) {
  const int blk = blockIdx.x;
  const int chunk = blk & 15;
  const int bg = blk >> 4;
  const int b = bg >> 5, g = bg & 31;
  const int t = threadIdx.x;
  const int p = chunk * 256 + t;
  const float* xp = x + (size_t)b * (4096 * 512) + (size_t)p * 512 + g * 16;
  float4 v0 = *(const float4*)(xp);
  float4 v1 = *(const float4*)(xp + 4);
  float4 v2 = *(const float4*)(xp + 8);
  float4 v3 = *(const float4*)(xp + 12);
  float s  = v0.x + v0.y + v0.z + v0.w + v1.x + v1.y + v1.z + v1.w
           + v2.x + v2.y + v2.z + v2.w + v3.x + v3.y + v3.z + v3.w;
  float ss = v0.x*v0.x + v0.y*v0.y + v0.z*v0.z + v0.w*v0.w
           + v1.x*v1.x + v1.y*v1.y + v1.z*v1.z + v1.w*v1.w
           + v2.x*v2.x + v2.y*v2.y + v2.z*v2.z + v2.w*v2.w
           + v3.x*v3.x + v3.y*v3.y + v3.z*v3.z + v3.w*v3.w;
#pragma unroll
  for (int off = 32; off; off >>= 1) {
    s  += __shfl_xor(s, off);
    ss += __shfl_xor(ss, off);
  }
  __shared__ float rs[4], rss[4];
  const int w = t >> 6, l = t & 63;
  if (l == 0) { rs[w] = s; rss[w] = ss; }
  __syncthreads();
  if (t == 0)
    part[blk] = make_float2(rs[0] + rs[1] + rs[2] + rs[3],
                            rss[0] + rss[1] + rss[2] + rss[3]);
}

__global__ void gn_finish_k(const float2* __restrict__ part,
                            float2* __restrict__ stats) {
  const int g = threadIdx.x;
  float s = 0.f, ss = 0.f;
#pragma unroll
  for (int c = 0; c < 16; ++c) {
    float2 p = part[g * 16 + c];
    s += p.x; ss += p.y;
  }
  float mean = s * (1.0f / 65536.0f);
  float var  = ss * (1.0f / 65536.0f) - mean * mean;
  stats[g] = make_float2(mean, 1.0f / sqrtf(var + 1e-6f));
}

// ---------------- normalize + bf16 cast ----------------
__global__ __launch_bounds__(256) void gn_apply_k(const float* __restrict__ x,
                                                  const float2* __restrict__ stats,
                                                  const float* __restrict__ gamma,
                                                  const float* __restrict__ beta,
                                                  bf16* __restrict__ xn) {
  size_t i = ((size_t)blockIdx.x * 256 + threadIdx.x) * 8;
  const int c = (int)(i & 511);
  const int b = (int)(i >> 21);
  float2 st = stats[b * 32 + (c >> 4)];
  float4 xa = *(const float4*)(x + i);
  float4 xb = *(const float4*)(x + i + 4);
  float4 ga = *(const float4*)(gamma + c);
  float4 gb = *(const float4*)(gamma + c + 4);
  float4 ba = *(const float4*)(beta + c);
  float4 bb = *(const float4*)(beta + c + 4);
  bf16x8 o;
  o[0] = (bf16)((xa.x - st.x) * st.y * ga.x + ba.x);
  o[1] = (bf16)((xa.y - st.x) * st.y * ga.y + ba.y);
  o[2] = (bf16)((xa.z - st.x) * st.y * ga.z + ba.z);
  o[3] = (bf16)((xa.w - st.x) * st.y * ga.w + ba.w);
  o[4] = (bf16)((xb.x - st.x) * st.y * gb.x + bb.x);
  o[5] = (bf16)((xb.y - st.x) * st.y * gb.y + bb.y);
  o[6] = (bf16)((xb.z - st.x) * st.y * gb.z + bb.z);
  o[7] = (bf16)((xb.w - st.x) * st.y * gb.w + bb.w);
  *(bf16x8*)(xn + i) = o;
}

// ---------------- weight transpose + bf16 convert ----------------
__global__ void prep_w_k(const float* __restrict__ wq, const float* __restrict__ wk,
                         const float* __restrict__ wv, const float* __restrict__ wo,
                         bf16* __restrict__ wt_qkv, bf16* __restrict__ wot, float qscale) {
  const int z = blockIdx.z;
  const float* W = (z == 0) ? wq : (z == 1) ? wk : (z == 2) ? wv : wo;
  bf16* dst = (z < 3) ? (wt_qkv + (size_t)z * 512 * 512) : wot;
  const float s = (z == 0) ? qscale : 1.0f;
  __shared__ float tile[32][33];
  const int i0 = blockIdx.y * 32;
  const int o0 = blockIdx.x * 32;
#pragma unroll
  for (int r = threadIdx.y; r < 32; r += 8)
    tile[r][threadIdx.x] = W[(size_t)(i0 + r) * 512 + o0 + threadIdx.x];
  __syncthreads();
#pragma unroll
  for (int r = threadIdx.y; r < 32; r += 8)
    dst[(size_t)(o0 + r) * 512 + i0 + threadIdx.x] = (bf16)(tile[threadIdx.x][r] * s);
}

__global__ void prep_bias_k(const float* __restrict__ bq, const float* __restrict__ bk,
                            const float* __restrict__ bv, float* __restrict__ bias_qkv,
                            float qscale) {
  int i = blockIdx.x * 256 + threadIdx.x;
  float v = (i < 512) ? bq[i] * qscale : (i < 1024) ? bk[i - 512] : bv[i - 1024];
  bias_qkv[i] = v;
}

// ---------------- V transpose ----------------
__global__ void transpose_v_k(const bf16* __restrict__ qkv, bf16* __restrict__ vt) {
  __shared__ bf16 tile[32][33];
  const int z = blockIdx.z;
  const int n0 = blockIdx.x * 32, d0 = blockIdx.y * 32;
  const bf16* src = qkv + (size_t)z * 4096 * 1536 + 1024;
#pragma unroll
  for (int r = threadIdx.y; r < 32; r += 8)
    tile[r][threadIdx.x] = src[(size_t)(n0 + r) * 1536 + d0 + threadIdx.x];
  __syncthreads();
  bf16* dst = vt + (size_t)z * 512 * 4096;
#pragma unroll
  for (int r = threadIdx.y; r < 32; r += 8)
    dst[(size_t)(d0 + r) * 4096 + n0 + threadIdx.x] = tile[threadIdx.x][r];
}

// ---------------- row softmax over 4096 bf16, in place ----------------
__global__ __launch_bounds__(256) void softmax_k(bf16* __restrict__ S) {
  const int t = threadIdx.x;
  bf16* p = S + (size_t)blockIdx.x * 4096 + t * 16;
  bf16x8 u0 = *(const bf16x8*)p;
  bf16x8 u1 = *(const bf16x8*)(p + 8);
  float v[16];
#pragma unroll
  for (int j = 0; j < 8; ++j) { v[j] = (float)u0[j]; v[j + 8] = (float)u1[j]; }
  float m = v[0];
#pragma unroll
  for (int j = 1; j < 16; ++j) m = fmaxf(m, v[j]);
#pragma unroll
  for (int off = 32; off; off >>= 1) m = fmaxf(m, __shfl_xor(m, off));
  __shared__ float red[4];
  const int w = t >> 6, l = t & 63;
  if (l == 0) red[w] = m;
  __syncthreads();
  m = fmaxf(fmaxf(red[0], red[1]), fmaxf(red[2], red[3]));
  __syncthreads();
  float s = 0.f;
#pragma unroll
  for (int j = 0; j < 16; ++j) { v[j] = __expf(v[j] - m); s += v[j]; }
#pragma unroll
  for (int off = 32; off; off >>= 1) s += __shfl_xor(s, off);
  if (l == 0) red[w] = s;
  __syncthreads();
  s = red[0] + red[1] + red[2] + red[3];
  const float inv = 1.0f / s;
#pragma unroll
  for (int j = 0; j < 8; ++j) { u0[j] = (bf16)(v[j] * inv); u1[j] = (bf16)(v[j + 8] * inv); }
  *(bf16x8*)p = u0;
  *(bf16x8*)(p + 8) = u1;
}

// ---------------- split-K reduce: attn = bf16(p0+p1) ----------------
__global__ __launch_bounds__(256) void reduce_pv_k(const float* __restrict__ p0,
                                                   const float* __restrict__ p1,
                                                   bf16* __restrict__ attn) {
  size_t i = ((size_t)blockIdx.x * 256 + threadIdx.x) * 8;
  float4 a = *(const float4*)(p0 + i);
  float4 b = *(const float4*)(p0 + i + 4);
  float4 c = *(const float4*)(p1 + i);
  float4 d = *(const float4*)(p1 + i + 4);
  bf16x8 o;
  o[0] = (bf16)(a.x + c.x); o[1] = (bf16)(a.y + c.y);
  o[2] = (bf16)(a.z + c.z); o[3] = (bf16)(a.w + c.w);
  o[4] = (bf16)(b.x + d.x); o[5] = (bf16)(b.y + d.y);
  o[6] = (bf16)(b.z + d.z); o[7] = (bf16)(b.w + d.w);
  *(bf16x8*)(attn + i) = o;
}

// ---------------- NT bf16 MFMA GEMM: BK=64, XOR-swizzled LDS (2-phase) -----
// Verified round-3 structure; used for the small-K QKV / out-proj GEMMs.
template <int BM, int BN, int EPI, int GX, int GY, int GZ>
__global__ __launch_bounds__(256, 2) void gemm_nt(
    const bf16* __restrict__ A, int lda, long sAz,
    const bf16* __restrict__ B, int ldb, long sBz,
    void* __restrict__ C, int ldc, long sCz,
    int nk,
    const float* __restrict__ bias,
    const float* __restrict__ resid) {
  constexpr int WM = BM / 2, WN = BN / 2;
  constexpr int FM = BM / 32, FN = BN / 32;
  constexpr int NWG = GX * GY * GZ;
  constexpr int CPX = NWG / 8;
  __shared__ alignas(16) bf16 As[2][BM * 64];
  __shared__ alignas(16) bf16 Bs[2][BN * 64];

  const int lin = blockIdx.x;
  const int wid = (lin & 7) * CPX + (lin >> 3);
  const int bx = wid % GX;
  const int by = (wid / GX) % GY;
  const int bz = wid / (GX * GY);

  const int t = threadIdx.x;
  const bf16* Aq = A + (size_t)bz * sAz + (size_t)by * BM * lda;
  const bf16* Bq = B + (size_t)bz * sBz + (size_t)bx * BN * ldb;

  const int srow = t >> 3;
  const int sg   = (t & 7) ^ (srow & 7);

  auto stage = [&](int buf, int kt) {
    const int k0 = kt * 64 + sg * 8;
#pragma unroll
    for (int i = 0; i < BM / 32; ++i)
      gload_lds16(Aq + (size_t)(i * 32 + srow) * lda + k0, &As[buf][i * 2048 + t * 8]);
#pragma unroll
    for (int i = 0; i < BN / 32; ++i)
      gload_lds16(Bq + (size_t)(i * 32 + srow) * ldb + k0, &Bs[buf][i * 2048 + t * 8]);
  };

  const int l = t & 63, w = t >> 6;
  const int wr = w >> 1, wc = w & 1;
  const int lr = l & 15, kh = l >> 4;
  const int rs = lr & 7;

  f32x4 acc[FM][FN] = {};

  stage(0, 0);
  for (int kt = 0; kt < nk; ++kt) {
    __syncthreads();
    if (kt + 1 < nk) stage((kt + 1) & 1, kt + 1);
    const int buf = kt & 1;
    bf16x8 a[2][FM], b[2][FN];
#pragma unroll
    for (int h = 0; h < 2; ++h) {
      const int g = ((h * 4 + kh) ^ rs) * 8;
#pragma unroll
      for (int m = 0; m < FM; ++m)
        a[h][m] = *(const bf16x8*)(&As[buf][(wr * WM + m * 16 + lr) * 64 + g]);
#pragma unroll
      for (int n = 0; n < FN; ++n)
        b[h][n] = *(const bf16x8*)(&Bs[buf][(wc * WN + n * 16 + lr) * 64 + g]);
    }
#pragma unroll
    for (int h = 0; h < 2; ++h)
#pragma unroll
      for (int m = 0; m < FM; ++m)
#pragma unroll
        for (int n = 0; n < FN; ++n)
          acc[m][n] = __builtin_amdgcn_mfma_f32_16x16x32_bf16(a[h][m], b[h][n], acc[m][n], 0, 0, 0);
  }

  const int gr0 = by * BM + wr * WM + kh * 4;
  const int gc0 = bx * BN + wc * WN + lr;
#pragma unroll
  for (int m = 0; m < FM; ++m)
#pragma unroll
    for (int n = 0; n < FN; ++n) {
      const int c = gc0 + n * 16;
      float bv = 0.f;
      if constexpr (EPI >= 1) bv = bias[c];
#pragma unroll
      for (int j = 0; j < 4; ++j) {
        const int r = gr0 + m * 16 + j;
        float val = acc[m][n][j] + bv;
        if constexpr (EPI == 2) {
          float* Cf = (float*)C + (size_t)bz * sCz;
          Cf[(size_t)r * ldc + c] = val + resid[(size_t)r * ldc + c];
        } else {
          bf16* Cb = (bf16*)C + (size_t)bz * sCz;
          Cb[(size_t)r * ldc + c] = (bf16)val;
        }
      }
    }
}

// ---------------- 8-phase NT GEMM (m201-style schedule, plain HIP) ---------
// C = A[M,K] * B[N,K]^T. 512 threads = 8 waves (WR x WC). BK=64, 2 LDS bufs.
// Iteration = 2 K-tiles (t0->buf0 phases P1-4, t1->buf1 phases P5-8).
// Each phase: {ds_read quadrant frags | stage ONE half-tile | bar |
//              setprio(1) MFMA quadrant setprio(0) | counted vmcnt | bar}.
// Stage windows (audited): t1 halves staged P1-4 (buf1 writable: its old
// tile's reads drained at prev P8 bar2); t0+2 halves staged P5-8 (buf0
// drained at P4 bar2). vmcnt gates: P2 allows t1.A0+A1 (=4 loads) -> t0.B1
// landed for P3; P4 allows t1.B1 (=LB) -> t1.A0,A1,B0 landed for P5;
// P6 allows t2.A0+A1 -> t1.B1 landed for P7 (last iter: vmcnt 0);
// P8 allows t2.B1 -> t2.A0,A1,B0 landed for next P1. Never 0 in steady state.
// EPI 0: bf16 store to C0. EPI 3: f32 partial store to (ks ? C1 : C0).
template <int BM, int BN, int WR, int WC, int EPI, int GX, int GY, int GZ, int KS>
__global__ __launch_bounds__(512, 2) void gemm_8p(
    const bf16* __restrict__ A, int lda, long sAz,
    const bf16* __restrict__ B, int ldb, long sBz,
    void* __restrict__ C0, void* __restrict__ C1, int ldc, long sCz,
    int nt) {
  constexpr int WM = BM / WR, WN = BN / WC;
  constexpr int FM = WM / 16, FN = WN / 16;
  constexpr int HM = FM / 2, HN = FN / 2;
  constexpr int LA = BM / 128, LB = BN / 128;
  constexpr int NWG = GX * KS * GY * GZ;
  constexpr int CPX = NWG / 8;
  static_assert(WR * WC == 8, "8 waves");
  static_assert(LA == 2 && (LB == 1 || LB == 2), "vmcnt literals");

  __shared__ alignas(16) bf16 As[2][BM * 64];
  __shared__ alignas(16) bf16 Bs[2][BN * 64];

  const int t = threadIdx.x;
  const int lin = blockIdx.x;
  const int wid = (lin & 7) * CPX + (lin >> 3);   // XCD-chunked, bijective
  const int bx = wid % GX;
  const int ks = (wid / GX) % KS;
  const int by = (wid / (GX * KS)) % GY;
  const int bz = wid / (GX * KS * GY);

  const long kOff = (long)ks * nt * 64;
  const bf16* Aq = A + (size_t)bz * sAz + (size_t)by * BM * lda + kOff;
  const bf16* Bq = B + (size_t)bz * sBz + (size_t)bx * BN * ldb + kOff;

  const int srow = t >> 3;                 // 0..63
  const int sgr  = (t & 7) ^ (srow & 7);   // pre-swizzled source granule

  // stage one half-tile (half*(BM/2) rows) of A or B into buf.
  auto stageA = [&](int buf, int tile, int half) {
    const bf16* src = Aq + (size_t)(half * (BM / 2) + srow) * lda + tile * 64 + sgr * 8;
    bf16* dst = &As[buf][(half * (BM / 2)) * 64] + t * 8;
#pragma unroll
    for (int j = 0; j < LA; ++j)
      gload_lds16(src + (size_t)(j * 64) * lda, dst + j * 4096);
  };
  auto stageB = [&](int buf, int tile, int half) {
    const bf16* src = Bq + (size_t)(half * (BN / 2) + srow) * ldb + tile * 64 + sgr * 8;
    bf16* dst = &Bs[buf][(half * (BN / 2)) * 64] + t * 8;
#pragma unroll
    for (int j = 0; j < LB; ++j)
      gload_lds16(src + (size_t)(j * 64) * ldb, dst + j * 4096);
  };

  const int l = t & 63, w = t >> 6;
  const int wr = w / WC, wc = w % WC;
  const int lr = l & 15, kh = l >> 4;
  const int rs8 = lr & 7;

  bf16x8 af[HM][2], bf_[HN][2];
  auto readA = [&](int buf, int qm) {
#pragma unroll
    for (int i = 0; i < HM; ++i)
#pragma unroll
      for (int h = 0; h < 2; ++h)
        af[i][h] = *(const bf16x8*)(
            &As[buf][(wr * WM + qm * (WM / 2) + i * 16 + lr) * 64 + (((h * 4 + kh) ^ rs8) * 8)]);
  };
  auto readB = [&](int buf, int qn) {
#pragma unroll
    for (int j = 0; j < HN; ++j)
#pragma unroll
      for (int h = 0; h < 2; ++h)
        bf_[j][h] = *(const bf16x8*)(
            &Bs[buf][(wc * WN + qn * (WN / 2) + j * 16 + lr) * 64 + (((h * 4 + kh) ^ rs8) * 8)]);
  };

  f32x4 acc[FM][FN] = {};

#define MFMAQ(QM, QN) { \
  __builtin_amdgcn_s_setprio(1); \
  _Pragma("unroll") for (int ii = 0; ii < HM; ++ii) \
  _Pragma("unroll") for (int jj = 0; jj < HN; ++jj) \
  _Pragma("unroll") for (int h = 0; h < 2; ++h) \
    acc[(QM)*HM + ii][(QN)*HN + jj] = __builtin_amdgcn_mfma_f32_16x16x32_bf16( \
        af[ii][h], bf_[jj][h], acc[(QM)*HM + ii][(QN)*HN + jj], 0, 0, 0); \
  __builtin_amdgcn_s_setprio(0); }
#define WAIT_LB() { if constexpr (LB == 1) VMCNT(1); else VMCNT(2); }

  // prologue: tile 0 -> buf0 (A0, A1, B0, B1)
  stageA(0, 0, 0); stageA(0, 0, 1); stageB(0, 0, 0); stageB(0, 0, 1);
  WAIT_LB();   // allow tile0.B1 outstanding; A0,A1,B0 landed
  BAR();

  const int half = nt >> 1;
  for (int i = 0; i < half; ++i) {
    const int t1 = 2 * i + 1, t2 = 2 * i + 2;
    const bool last = (i == half - 1);
    // ---- P1: quadrant (0,0) of buf0 ----
    readA(0, 0); readB(0, 0);
    stageA(1, t1, 0);
    BAR();
    MFMAQ(0, 0);
    BAR();
    // ---- P2: (1,0) ----
    readA(0, 1);
    stageA(1, t1, 1);
    BAR();
    MFMAQ(1, 0);
    VMCNT(4);                 // gate t0.B1 (allow t1.A0+A1)
    BAR();
    // ---- P3: (1,1) ----
    readB(0, 1);
    stageB(1, t1, 0);
    BAR();
    MFMAQ(1, 1);
    BAR();
    // ---- P4: (0,1) ----
    readA(0, 0);
    stageB(1, t1, 1);
    BAR();
    MFMAQ(0, 1);
    WAIT_LB();                // gate t1.A0,A1,B0 (allow t1.B1)
    BAR();
    // ---- P5: (0,0) of buf1 ----
    readA(1, 0); readB(1, 0);
    if (!last) stageA(0, t2, 0);
    BAR();
    MFMAQ(0, 0);
    BAR();
    // ---- P6: (1,0) ----
    readA(1, 1);
    if (!last) stageA(0, t2, 1);
    BAR();
    MFMAQ(1, 0);
    if (last) { VMCNT(0); } else { VMCNT(4); }   // gate t1.B1
    BAR();
    // ---- P7: (1,1) ----
    readB(1, 1);
    if (!last) stageB(0, t2, 0);
    BAR();
    MFMAQ(1, 1);
    BAR();
    // ---- P8: (0,1) ----
    readA(1, 0);
    if (!last) stageB(0, t2, 1);
    BAR();
    MFMAQ(0, 1);
    WAIT_LB();                // gate t2.A0,A1,B0 (trivial on last)
    BAR();
  }
#undef MFMAQ
#undef WAIT_LB

  // epilogue: C/D layout col = lane&15, row = (lane>>4)*4 + reg
  const int gr0 = by * BM + wr * WM + kh * 4;
  const int gc0 = bx * BN + wc * WN + lr;
#pragma unroll
  for (int m = 0; m < FM; ++m)
#pragma unroll
    for (int n = 0; n < FN; ++n) {
      const int c = gc0 + n * 16;
#pragma unroll
      for (int j = 0; j < 4; ++j) {
        const int r = gr0 + m * 16 + j;
        if constexpr (EPI == 0) {
          bf16* Cb = (bf16*)C0 + (size_t)bz * sCz;
          Cb[(size_t)r * ldc + c] = (bf16)acc[m][n][j];
        } else {  // EPI == 3: f32 split-K partial
          float* Cf = (float*)(ks ? C1 : C0) + (size_t)bz * sCz;
          Cf[(size_t)r * ldc + c] = acc[m][n][j];
        }
      }
    }
}

// ---------------- launch ----------------
extern "C" void kernel_launch(void* const* d_in, const int* in_sizes, int n_in,
                              void* d_out, int out_size, void* d_ws, size_t ws_size,
                              hipStream_t stream) {
  const float* x     = (const float*)d_in[0];
  const float* gamma = (const float*)d_in[1];
  const float* beta  = (const float*)d_in[2];
  const float* wq = (const float*)d_in[3];
  const float* bq = (const float*)d_in[4];
  const float* wk = (const float*)d_in[5];
  const float* bk = (const float*)d_in[6];
  const float* wv = (const float*)d_in[7];
  const float* bv = (const float*)d_in[8];
  const float* wo = (const float*)d_in[9];
  const float* bo = (const float*)d_in[10];
  float* out = (float*)d_out;
  char* ws = (char*)d_ws;

  float2* stats    = (float2*)(ws + OFF_STATS);
  bf16*   wot      = (bf16*)(ws + OFF_WOT);
  float*  bias_qkv = (float*)(ws + OFF_BIASQ);
  bf16*   wt_qkv   = (bf16*)(ws + OFF_WTQKV);
  bf16*   xn       = (bf16*)(ws + OFF_XN);
  bf16*   qkv      = (bf16*)(ws + OFF_QKV);
  bf16*   vt       = (bf16*)(ws + OFF_VT);
  bf16*   S        = (bf16*)(ws + OFF_S);
  float*  p0       = (float*)(ws + OFF_P0);
  float*  p1       = (float*)(ws + OFF_P1);
  bf16*   attn     = (bf16*)(ws + OFF_ATTN);
  float2* gn_part  = (float2*)(ws + OFF_GNP);

  const float qscale = 0.04419417382415922f;  // 1/sqrt(512)

  prep_w_k<<<dim3(16, 16, 4), dim3(32, 8), 0, stream>>>(wq, wk, wv, wo, wt_qkv, wot, qscale);
  prep_bias_k<<<6, 256, 0, stream>>>(bq, bk, bv, bias_qkv, qscale);
  gn_part_k<<<1024, 256, 0, stream>>>(x, gn_part);
  gn_finish_k<<<1, 64, 0, stream>>>(gn_part, stats);
  gn_apply_k<<<2048, 256, 0, stream>>>(x, stats, gamma, beta, xn);

  // QKV: [8192,512] @ WT[1536,512]^T -> qkv [8192,1536]  (2-phase, verified)
  gemm_nt<128, 128, 1, 12, 64, 1><<<768, 256, 0, stream>>>(
      xn, 512, 0, wt_qkv, 512, 0, qkv, 1536, 0, 512 / 64, bias_qkv, nullptr);

  // scores: per batch S[4096,4096] = q @ k^T  (8-phase 256^2)
  gemm_8p<256, 256, 2, 4, 0, 16, 16, 2, 1><<<512, 512, 0, stream>>>(
      qkv, 1536, 4096L * 1536, qkv + 512, 1536, 4096L * 1536,
      S, nullptr, 4096, 4096L * 4096, 512 / 64);

  softmax_k<<<8192, 256, 0, stream>>>(S);

  transpose_v_k<<<dim3(128, 16, 2), dim3(32, 8), 0, stream>>>(qkv, vt);

  // PV: per batch [4096,512] = P @ VT^T  (8-phase 256x128, split-K=2 -> f32)
  gemm_8p<256, 128, 4, 2, 3, 4, 16, 2, 2><<<256, 512, 0, stream>>>(
      S, 4096, 4096L * 4096, vt, 4096, 512L * 4096,
      p0, p1, 512, 4096L * 512, 2048 / 64);

  reduce_pv_k<<<2048, 256, 0, stream>>>(p0, p1, attn);

  // out: [8192,512] = attn @ WOT^T + bo + inputs (fp32)
  gemm_nt<64, 128, 2, 4, 128, 1><<<512, 256, 0, stream>>>(
      attn, 512, 0, wot, 512, 0, out, 512, 0, 512 / 64, bo, x);
}

// Round 8
// 163.074 us; speedup vs baseline: 1.0832x; 1.0832x over previous
//
#include <hip/hip_runtime.h>
#include <math.h>

typedef __bf16 bf16;
typedef __bf16 bf16x8 __attribute__((ext_vector_type(8)));
typedef float  f32x4  __attribute__((ext_vector_type(4)));

#define DEV __device__ __forceinline__
#define VMCNT(n) asm volatile("s_waitcnt vmcnt(" #n ")" ::: "memory")
#define CFENCE  asm volatile("" ::: "memory")
#define BAR()   { CFENCE; __builtin_amdgcn_s_barrier(); CFENCE; }

DEV void gload_lds16(const bf16* g, bf16* l) {
  __builtin_amdgcn_global_load_lds(
      (const __attribute__((address_space(1))) void*)g,
      (__attribute__((address_space(3))) void*)l, 16, 0, 0);
}

// ---------------- workspace layout (bytes) ----------------
#define OFF_STATS 0UL
#define OFF_WOT   1024UL        // 512*512*2 = 524288            -> 525312
#define OFF_BIASQ 525312UL      // 1536*4    = 6144              -> 531456
#define OFF_WTQKV 531456UL      // 1536*512*2 = 1572864          -> 2104320
#define OFF_XN    2104320UL     // 8192*512*2 = 8388608          -> 10492928
#define OFF_QKV   10492928UL    // 8192*1536*2 = 25165824        -> 35658752
#define OFF_VT    35658752UL    // 2*512*4096*2 = 8388608        -> 44047360
#define OFF_S     44047360UL    // 2*4096*4096*2 = 67108864      -> 111156224
#define OFF_LSUM  111156224UL   // 8192*64*4 = 2097152           -> 113253376
#define OFF_INVL  113253376UL   // 8192*4 = 32768                -> 113286144
// overlays (stream-ordered lifetimes):
#define OFF_P0    2104320UL     // f32 2*4096*512*4 = 16777216 (xn/qkv dead at PV)
#define OFF_P1    18881536UL    // ends 35658752 == OFF_VT exactly
#define OFF_ATTN  44047360UL    // overlays S (dead after PV; reduce runs after)
#define OFF_GNP   44047360UL    // gn partials, prep-time only

// ---------------- GroupNorm partial stats: 1024 blocks ----------------
__global__ __launch_bounds__(256) void gn_part_k(const float* __restrict__ x,
                                                 float2* __restrict__ part) {
  const int blk = blockIdx.x;
  const int chunk = blk & 15;
  const int bg = blk >> 4;
  const int b = bg >> 5, g = bg & 31;
  const int t = threadIdx.x;
  const int p = chunk * 256 + t;
  const float* xp = x + (size_t)b * (4096 * 512) + (size_t)p * 512 + g * 16;
  float4 v0 = *(const float4*)(xp);
  float4 v1 = *(const float4*)(xp + 4);
  float4 v2 = *(const float4*)(xp + 8);
  float4 v3 = *(const float4*)(xp + 12);
  float s  = v0.x + v0.y + v0.z + v0.w + v1.x + v1.y + v1.z + v1.w
           + v2.x + v2.y + v2.z + v2.w + v3.x + v3.y + v3.z + v3.w;
  float ss = v0.x*v0.x + v0.y*v0.y + v0.z*v0.z + v0.w*v0.w
           + v1.x*v1.x + v1.y*v1.y + v1.z*v1.z + v1.w*v1.w
           + v2.x*v2.x + v2.y*v2.y + v2.z*v2.z + v2.w*v2.w
           + v3.x*v3.x + v3.y*v3.y + v3.z*v3.z + v3.w*v3.w;
#pragma unroll
  for (int off = 32; off; off >>= 1) {
    s  += __shfl_xor(s, off);
    ss += __shfl_xor(ss, off);
  }
  __shared__ float rs[4], rss[4];
  const int w = t >> 6, l = t & 63;
  if (l == 0) { rs[w] = s; rss[w] = ss; }
  __syncthreads();
  if (t == 0)
    part[blk] = make_float2(rs[0] + rs[1] + rs[2] + rs[3],
                            rss[0] + rss[1] + rss[2] + rss[3]);
}

__global__ void gn_finish_k(const float2* __restrict__ part,
                            float2* __restrict__ stats) {
  const int g = threadIdx.x;
  float s = 0.f, ss = 0.f;
#pragma unroll
  for (int c = 0; c < 16; ++c) {
    float2 p = part[g * 16 + c];
    s += p.x; ss += p.y;
  }
  float mean = s * (1.0f / 65536.0f);
  float var  = ss * (1.0f / 65536.0f) - mean * mean;
  stats[g] = make_float2(mean, 1.0f / sqrtf(var + 1e-6f));
}

// ---------------- normalize + bf16 cast ----------------
__global__ __launch_bounds__(256) void gn_apply_k(const float* __restrict__ x,
                                                  const float2* __restrict__ stats,
                                                  const float* __restrict__ gamma,
                                                  const float* __restrict__ beta,
                                                  bf16* __restrict__ xn) {
  size_t i = ((size_t)blockIdx.x * 256 + threadIdx.x) * 8;
  const int c = (int)(i & 511);
  const int b = (int)(i >> 21);
  float2 st = stats[b * 32 + (c >> 4)];
  float4 xa = *(const float4*)(x + i);
  float4 xb = *(const float4*)(x + i + 4);
  float4 ga = *(const float4*)(gamma + c);
  float4 gb = *(const float4*)(gamma + c + 4);
  float4 ba = *(const float4*)(beta + c);
  float4 bb = *(const float4*)(beta + c + 4);
  bf16x8 o;
  o[0] = (bf16)((xa.x - st.x) * st.y * ga.x + ba.x);
  o[1] = (bf16)((xa.y - st.x) * st.y * ga.y + ba.y);
  o[2] = (bf16)((xa.z - st.x) * st.y * ga.z + ba.z);
  o[3] = (bf16)((xa.w - st.x) * st.y * ga.w + ba.w);
  o[4] = (bf16)((xb.x - st.x) * st.y * gb.x + bb.x);
  o[5] = (bf16)((xb.y - st.x) * st.y * gb.y + bb.y);
  o[6] = (bf16)((xb.z - st.x) * st.y * gb.z + bb.z);
  o[7] = (bf16)((xb.w - st.x) * st.y * gb.w + bb.w);
  *(bf16x8*)(xn + i) = o;
}

// ---------------- weight transpose + bf16 convert ----------------
__global__ void prep_w_k(const float* __restrict__ wq, const float* __restrict__ wk,
                         const float* __restrict__ wv, const float* __restrict__ wo,
                         bf16* __restrict__ wt_qkv, bf16* __restrict__ wot, float qscale) {
  const int z = blockIdx.z;
  const float* W = (z == 0) ? wq : (z == 1) ? wk : (z == 2) ? wv : wo;
  bf16* dst = (z < 3) ? (wt_qkv + (size_t)z * 512 * 512) : wot;
  const float s = (z == 0) ? qscale : 1.0f;
  __shared__ float tile[32][33];
  const int i0 = blockIdx.y * 32;
  const int o0 = blockIdx.x * 32;
#pragma unroll
  for (int r = threadIdx.y; r < 32; r += 8)
    tile[r][threadIdx.x] = W[(size_t)(i0 + r) * 512 + o0 + threadIdx.x];
  __syncthreads();
#pragma unroll
  for (int r = threadIdx.y; r < 32; r += 8)
    dst[(size_t)(o0 + r) * 512 + i0 + threadIdx.x] = (bf16)(tile[threadIdx.x][r] * s);
}

__global__ void prep_bias_k(const float* __restrict__ bq, const float* __restrict__ bk,
                            const float* __restrict__ bv, float* __restrict__ bias_qkv,
                            float qscale) {
  int i = blockIdx.x * 256 + threadIdx.x;
  float v = (i < 512) ? bq[i] * qscale : (i < 1024) ? bk[i - 512] : bv[i - 1024];
  bias_qkv[i] = v;
}

// ---------------- V transpose ----------------
__global__ void transpose_v_k(const bf16* __restrict__ qkv, bf16* __restrict__ vt) {
  __shared__ bf16 tile[32][33];
  const int z = blockIdx.z;
  const int n0 = blockIdx.x * 32, d0 = blockIdx.y * 32;
  const bf16* src = qkv + (size_t)z * 4096 * 1536 + 1024;
#pragma unroll
  for (int r = threadIdx.y; r < 32; r += 8)
    tile[r][threadIdx.x] = src[(size_t)(n0 + r) * 1536 + d0 + threadIdx.x];
  __syncthreads();
  bf16* dst = vt + (size_t)z * 512 * 4096;
#pragma unroll
  for (int r = threadIdx.y; r < 32; r += 8)
    dst[(size_t)(d0 + r) * 4096 + n0 + threadIdx.x] = tile[threadIdx.x][r];
}

// ---------------- denom: inv_l[row] = 1 / sum of 64 partials ----------------
__global__ __launch_bounds__(256) void inv_l_k(const float* __restrict__ lsum,
                                               float* __restrict__ invl) {
  const int r = blockIdx.x * 256 + threadIdx.x;   // 0..8191
  const float* p = lsum + (size_t)r * 64;
  float s = 0.f;
#pragma unroll
  for (int k = 0; k < 64; k += 4) {
    float4 v = *(const float4*)(p + k);
    s += v.x + v.y + v.z + v.w;
  }
  invl[r] = 1.0f / s;
}

// ---------------- split-K reduce + softmax normalize ----------------
__global__ __launch_bounds__(256) void reduce_pv_k(const float* __restrict__ p0,
                                                   const float* __restrict__ p1,
                                                   const float* __restrict__ invl,
                                                   bf16* __restrict__ attn) {
  size_t i = ((size_t)blockIdx.x * 256 + threadIdx.x) * 8;
  const float il = invl[i >> 9];          // 512 cols per row
  float4 a = *(const float4*)(p0 + i);
  float4 b = *(const float4*)(p0 + i + 4);
  float4 c = *(const float4*)(p1 + i);
  float4 d = *(const float4*)(p1 + i + 4);
  bf16x8 o;
  o[0] = (bf16)((a.x + c.x) * il); o[1] = (bf16)((a.y + c.y) * il);
  o[2] = (bf16)((a.z + c.z) * il); o[3] = (bf16)((a.w + c.w) * il);
  o[4] = (bf16)((b.x + d.x) * il); o[5] = (bf16)((b.y + d.y) * il);
  o[6] = (bf16)((b.z + d.z) * il); o[7] = (bf16)((b.w + d.w) * il);
  *(bf16x8*)(attn + i) = o;
}

// ---------------- NT bf16 MFMA GEMM: BK=64, XOR-swizzled LDS (2-phase) -----
template <int BM, int BN, int EPI, int GX, int GY, int GZ>
__global__ __launch_bounds__(256, 2) void gemm_nt(
    const bf16* __restrict__ A, int lda, long sAz,
    const bf16* __restrict__ B, int ldb, long sBz,
    void* __restrict__ C, int ldc, long sCz,
    int nk,
    const float* __restrict__ bias,
    const float* __restrict__ resid) {
  constexpr int WM = BM / 2, WN = BN / 2;
  constexpr int FM = BM / 32, FN = BN / 32;
  constexpr int NWG = GX * GY * GZ;
  constexpr int CPX = NWG / 8;
  __shared__ alignas(16) bf16 As[2][BM * 64];
  __shared__ alignas(16) bf16 Bs[2][BN * 64];

  const int lin = blockIdx.x;
  const int wid = (lin & 7) * CPX + (lin >> 3);
  const int bx = wid % GX;
  const int by = (wid / GX) % GY;
  const int bz = wid / (GX * GY);

  const int t = threadIdx.x;
  const bf16* Aq = A + (size_t)bz * sAz + (size_t)by * BM * lda;
  const bf16* Bq = B + (size_t)bz * sBz + (size_t)bx * BN * ldb;

  const int srow = t >> 3;
  const int sg   = (t & 7) ^ (srow & 7);

  auto stage = [&](int buf, int kt) {
    const int k0 = kt * 64 + sg * 8;
#pragma unroll
    for (int i = 0; i < BM / 32; ++i)
      gload_lds16(Aq + (size_t)(i * 32 + srow) * lda + k0, &As[buf][i * 2048 + t * 8]);
#pragma unroll
    for (int i = 0; i < BN / 32; ++i)
      gload_lds16(Bq + (size_t)(i * 32 + srow) * ldb + k0, &Bs[buf][i * 2048 + t * 8]);
  };

  const int l = t & 63, w = t >> 6;
  const int wr = w >> 1, wc = w & 1;
  const int lr = l & 15, kh = l >> 4;
  const int rs = lr & 7;

  f32x4 acc[FM][FN] = {};

  stage(0, 0);
  for (int kt = 0; kt < nk; ++kt) {
    __syncthreads();
    if (kt + 1 < nk) stage((kt + 1) & 1, kt + 1);
    const int buf = kt & 1;
    bf16x8 a[2][FM], b[2][FN];
#pragma unroll
    for (int h = 0; h < 2; ++h) {
      const int g = ((h * 4 + kh) ^ rs) * 8;
#pragma unroll
      for (int m = 0; m < FM; ++m)
        a[h][m] = *(const bf16x8*)(&As[buf][(wr * WM + m * 16 + lr) * 64 + g]);
#pragma unroll
      for (int n = 0; n < FN; ++n)
        b[h][n] = *(const bf16x8*)(&Bs[buf][(wc * WN + n * 16 + lr) * 64 + g]);
    }
#pragma unroll
    for (int h = 0; h < 2; ++h)
#pragma unroll
      for (int m = 0; m < FM; ++m)
#pragma unroll
        for (int n = 0; n < FN; ++n)
          acc[m][n] = __builtin_amdgcn_mfma_f32_16x16x32_bf16(a[h][m], b[h][n], acc[m][n], 0, 0, 0);
  }

  const int gr0 = by * BM + wr * WM + kh * 4;
  const int gc0 = bx * BN + wc * WN + lr;
#pragma unroll
  for (int m = 0; m < FM; ++m)
#pragma unroll
    for (int n = 0; n < FN; ++n) {
      const int c = gc0 + n * 16;
      float bv = 0.f;
      if constexpr (EPI >= 1) bv = bias[c];
#pragma unroll
      for (int j = 0; j < 4; ++j) {
        const int r = gr0 + m * 16 + j;
        float val = acc[m][n][j] + bv;
        if constexpr (EPI == 2) {
          float* Cf = (float*)C + (size_t)bz * sCz;
          Cf[(size_t)r * ldc + c] = val + resid[(size_t)r * ldc + c];
        } else {
          bf16* Cb = (bf16*)C + (size_t)bz * sCz;
          Cb[(size_t)r * ldc + c] = (bf16)val;
        }
      }
    }
}

// ---------------- 8-phase NT GEMM (round-7 schedule, audited) --------------
// EPI 0: bf16 store. EPI 3: f32 split-K partial to (ks ? C1 : C0).
// EPI 4: P = exp(s) bf16 store + per-row partial sums -> LS[row][bx*WC+wc]
//        (unnormalized softmax; normalization happens in reduce_pv via inv_l).
template <int BM, int BN, int WR, int WC, int EPI, int GX, int GY, int GZ, int KS>
__global__ __launch_bounds__(512, 2) void gemm_8p(
    const bf16* __restrict__ A, int lda, long sAz,
    const bf16* __restrict__ B, int ldb, long sBz,
    void* __restrict__ C0, void* __restrict__ C1, int ldc, long sCz,
    int nt, float* __restrict__ LS) {
  constexpr int WM = BM / WR, WN = BN / WC;
  constexpr int FM = WM / 16, FN = WN / 16;
  constexpr int HM = FM / 2, HN = FN / 2;
  constexpr int LA = BM / 128, LB = BN / 128;
  constexpr int NWG = GX * KS * GY * GZ;
  constexpr int CPX = NWG / 8;
  static_assert(WR * WC == 8, "8 waves");
  static_assert(LA == 2 && (LB == 1 || LB == 2), "vmcnt literals");

  __shared__ alignas(16) bf16 As[2][BM * 64];
  __shared__ alignas(16) bf16 Bs[2][BN * 64];

  const int t = threadIdx.x;
  const int lin = blockIdx.x;
  const int wid = (lin & 7) * CPX + (lin >> 3);
  const int bx = wid % GX;
  const int ks = (wid / GX) % KS;
  const int by = (wid / (GX * KS)) % GY;
  const int bz = wid / (GX * KS * GY);

  const long kOff = (long)ks * nt * 64;
  const bf16* Aq = A + (size_t)bz * sAz + (size_t)by * BM * lda + kOff;
  const bf16* Bq = B + (size_t)bz * sBz + (size_t)bx * BN * ldb + kOff;

  const int srow = t >> 3;
  const int sgr  = (t & 7) ^ (srow & 7);

  auto stageA = [&](int buf, int tile, int half) {
    const bf16* src = Aq + (size_t)(half * (BM / 2) + srow) * lda + tile * 64 + sgr * 8;
    bf16* dst = &As[buf][(half * (BM / 2)) * 64] + t * 8;
#pragma unroll
    for (int j = 0; j < LA; ++j)
      gload_lds16(src + (size_t)(j * 64) * lda, dst + j * 4096);
  };
  auto stageB = [&](int buf, int tile, int half) {
    const bf16* src = Bq + (size_t)(half * (BN / 2) + srow) * ldb + tile * 64 + sgr * 8;
    bf16* dst = &Bs[buf][(half * (BN / 2)) * 64] + t * 8;
#pragma unroll
    for (int j = 0; j < LB; ++j)
      gload_lds16(src + (size_t)(j * 64) * ldb, dst + j * 4096);
  };

  const int l = t & 63, w = t >> 6;
  const int wr = w / WC, wc = w % WC;
  const int lr = l & 15, kh = l >> 4;
  const int rs8 = lr & 7;

  bf16x8 af[HM][2], bf_[HN][2];
  auto readA = [&](int buf, int qm) {
#pragma unroll
    for (int i = 0; i < HM; ++i)
#pragma unroll
      for (int h = 0; h < 2; ++h)
        af[i][h] = *(const bf16x8*)(
            &As[buf][(wr * WM + qm * (WM / 2) + i * 16 + lr) * 64 + (((h * 4 + kh) ^ rs8) * 8)]);
  };
  auto readB = [&](int buf, int qn) {
#pragma unroll
    for (int j = 0; j < HN; ++j)
#pragma unroll
      for (int h = 0; h < 2; ++h)
        bf_[j][h] = *(const bf16x8*)(
            &Bs[buf][(wc * WN + qn * (WN / 2) + j * 16 + lr) * 64 + (((h * 4 + kh) ^ rs8) * 8)]);
  };

  f32x4 acc[FM][FN] = {};

#define MFMAQ(QM, QN) { \
  __builtin_amdgcn_s_setprio(1); \
  _Pragma("unroll") for (int ii = 0; ii < HM; ++ii) \
  _Pragma("unroll") for (int jj = 0; jj < HN; ++jj) \
  _Pragma("unroll") for (int h = 0; h < 2; ++h) \
    acc[(QM)*HM + ii][(QN)*HN + jj] = __builtin_amdgcn_mfma_f32_16x16x32_bf16( \
        af[ii][h], bf_[jj][h], acc[(QM)*HM + ii][(QN)*HN + jj], 0, 0, 0); \
  __builtin_amdgcn_s_setprio(0); }
#define WAIT_LB() { if constexpr (LB == 1) VMCNT(1); else VMCNT(2); }

  stageA(0, 0, 0); stageA(0, 0, 1); stageB(0, 0, 0); stageB(0, 0, 1);
  WAIT_LB();
  BAR();

  const int half = nt >> 1;
  for (int i = 0; i < half; ++i) {
    const int t1 = 2 * i + 1, t2 = 2 * i + 2;
    const bool last = (i == half - 1);
    readA(0, 0); readB(0, 0);
    stageA(1, t1, 0);
    BAR();
    MFMAQ(0, 0);
    BAR();
    readA(0, 1);
    stageA(1, t1, 1);
    BAR();
    MFMAQ(1, 0);
    VMCNT(4);
    BAR();
    readB(0, 1);
    stageB(1, t1, 0);
    BAR();
    MFMAQ(1, 1);
    BAR();
    readA(0, 0);
    stageB(1, t1, 1);
    BAR();
    MFMAQ(0, 1);
    WAIT_LB();
    BAR();
    readA(1, 0); readB(1, 0);
    if (!last) stageA(0, t2, 0);
    BAR();
    MFMAQ(0, 0);
    BAR();
    readA(1, 1);
    if (!last) stageA(0, t2, 1);
    BAR();
    MFMAQ(1, 0);
    if (last) { VMCNT(0); } else { VMCNT(4); }
    BAR();
    readB(1, 1);
    if (!last) stageB(0, t2, 0);
    BAR();
    MFMAQ(1, 1);
    BAR();
    readA(1, 0);
    if (!last) stageB(0, t2, 1);
    BAR();
    MFMAQ(0, 1);
    WAIT_LB();
    BAR();
  }
#undef MFMAQ
#undef WAIT_LB

  // epilogue: C/D layout col = lane&15, row = (lane>>4)*4 + reg
  const int gr0 = by * BM + wr * WM + kh * 4;
  const int gc0 = bx * BN + wc * WN + lr;
  if constexpr (EPI == 4) {
    bf16* Cb = (bf16*)C0 + (size_t)bz * sCz;
    float rsum[FM][4];
#pragma unroll
    for (int m = 0; m < FM; ++m)
#pragma unroll
      for (int j = 0; j < 4; ++j) rsum[m][j] = 0.f;
#pragma unroll
    for (int m = 0; m < FM; ++m)
#pragma unroll
      for (int n = 0; n < FN; ++n) {
        const int c = gc0 + n * 16;
#pragma unroll
        for (int j = 0; j < 4; ++j) {
          const int r = gr0 + m * 16 + j;
          float e = __expf(acc[m][n][j]);
          Cb[(size_t)r * ldc + c] = (bf16)e;
          rsum[m][j] += e;
        }
      }
    // reduce across the 16 lanes (lr) that share the same rows
#pragma unroll
    for (int m = 0; m < FM; ++m)
#pragma unroll
      for (int j = 0; j < 4; ++j) {
        float v = rsum[m][j];
        v += __shfl_xor(v, 1); v += __shfl_xor(v, 2);
        v += __shfl_xor(v, 4); v += __shfl_xor(v, 8);
        rsum[m][j] = v;
      }
    if (lr == 0) {
#pragma unroll
      for (int m = 0; m < FM; ++m)
#pragma unroll
        for (int j = 0; j < 4; ++j) {
          const int r = gr0 + m * 16 + j;    // row within batch (0..4095)
          LS[((size_t)bz * 4096 + r) * (GX * WC) + bx * WC + wc] = rsum[m][j];
        }
    }
  } else {
#pragma unroll
    for (int m = 0; m < FM; ++m)
#pragma unroll
      for (int n = 0; n < FN; ++n) {
        const int c = gc0 + n * 16;
#pragma unroll
        for (int j = 0; j < 4; ++j) {
          const int r = gr0 + m * 16 + j;
          if constexpr (EPI == 0) {
            bf16* Cb = (bf16*)C0 + (size_t)bz * sCz;
            Cb[(size_t)r * ldc + c] = (bf16)acc[m][n][j];
          } else {  // EPI == 3
            float* Cf = (float*)(ks ? C1 : C0) + (size_t)bz * sCz;
            Cf[(size_t)r * ldc + c] = acc[m][n][j];
          }
        }
      }
  }
}

// ---------------- launch ----------------
extern "C" void kernel_launch(void* const* d_in, const int* in_sizes, int n_in,
                              void* d_out, int out_size, void* d_ws, size_t ws_size,
                              hipStream_t stream) {
  const float* x     = (const float*)d_in[0];
  const float* gamma = (const float*)d_in[1];
  const float* beta  = (const float*)d_in[2];
  const float* wq = (const float*)d_in[3];
  const float* bq = (const float*)d_in[4];
  const float* wk = (const float*)d_in[5];
  const float* bk = (const float*)d_in[6];
  const float* wv = (const float*)d_in[7];
  const float* bv = (const float*)d_in[8];
  const float* wo = (const float*)d_in[9];
  const float* bo = (const float*)d_in[10];
  float* out = (float*)d_out;
  char* ws = (char*)d_ws;

  float2* stats    = (float2*)(ws + OFF_STATS);
  bf16*   wot      = (bf16*)(ws + OFF_WOT);
  float*  bias_qkv = (float*)(ws + OFF_BIASQ);
  bf16*   wt_qkv   = (bf16*)(ws + OFF_WTQKV);
  bf16*   xn       = (bf16*)(ws + OFF_XN);
  bf16*   qkv      = (bf16*)(ws + OFF_QKV);
  bf16*   vt       = (bf16*)(ws + OFF_VT);
  bf16*   S        = (bf16*)(ws + OFF_S);
  float*  lsum     = (float*)(ws + OFF_LSUM);
  float*  invl     = (float*)(ws + OFF_INVL);
  float*  p0       = (float*)(ws + OFF_P0);
  float*  p1       = (float*)(ws + OFF_P1);
  bf16*   attn     = (bf16*)(ws + OFF_ATTN);
  float2* gn_part  = (float2*)(ws + OFF_GNP);

  const float qscale = 0.04419417382415922f;  // 1/sqrt(512)

  prep_w_k<<<dim3(16, 16, 4), dim3(32, 8), 0, stream>>>(wq, wk, wv, wo, wt_qkv, wot, qscale);
  prep_bias_k<<<6, 256, 0, stream>>>(bq, bk, bv, bias_qkv, qscale);
  gn_part_k<<<1024, 256, 0, stream>>>(x, gn_part);
  gn_finish_k<<<1, 64, 0, stream>>>(gn_part, stats);
  gn_apply_k<<<2048, 256, 0, stream>>>(x, stats, gamma, beta, xn);

  // QKV: [8192,512] @ WT[1536,512]^T -> qkv [8192,1536]  (2-phase, verified)
  gemm_nt<128, 128, 1, 12, 64, 1><<<768, 256, 0, stream>>>(
      xn, 512, 0, wt_qkv, 512, 0, qkv, 1536, 0, 512 / 64, bias_qkv, nullptr);

  // scores+exp: per batch P[4096,4096] = exp(q @ k^T), row-sum partials -> lsum
  gemm_8p<256, 256, 2, 4, 4, 16, 16, 2, 1><<<512, 512, 0, stream>>>(
      qkv, 1536, 4096L * 1536, qkv + 512, 1536, 4096L * 1536,
      S, nullptr, 4096, 4096L * 4096, 512 / 64, lsum);

  inv_l_k<<<32, 256, 0, stream>>>(lsum, invl);

  transpose_v_k<<<dim3(128, 16, 2), dim3(32, 8), 0, stream>>>(qkv, vt);

  // PV: per batch [4096,512] = P @ VT^T  (8-phase 256x128, split-K=2 -> f32)
  gemm_8p<256, 128, 4, 2, 3, 4, 16, 2, 2><<<256, 512, 0, stream>>>(
      S, 4096, 4096L * 4096, vt, 4096, 512L * 4096,
      p0, p1, 512, 4096L * 512, 2048 / 64, nullptr);

  // reduce + normalize: attn = bf16((p0+p1) * inv_l[row])
  reduce_pv_k<<<2048, 256, 0, stream>>>(p0, p1, invl, attn);

  // out: [8192,512] = attn @ WOT^T + bo + inputs (fp32)
  gemm_nt<64, 128, 2, 4, 128, 1><<<512, 256, 0, stream>>>(
      attn, 512, 0, wot, 512, 0, out, 512, 0, 512 / 64, bo, x);
}